// Round 21
// baseline (120.236 us; speedup 1.0000x reference)
//
#include <hip/hip_runtime.h>
#include <hip/hip_bf16.h>
#include <cstdint>
#include <cstddef>

#define S_LEN 2048
#define DMODEL 1024
#define NHEAD 16
#define HDK 64
#define LOG2E 1.44269504088896340736f

typedef __attribute__((ext_vector_type(8))) __bf16 bf16x8;
typedef __attribute__((ext_vector_type(4))) __bf16 bf16x4;
typedef __attribute__((ext_vector_type(4))) float f32x4;
typedef __attribute__((ext_vector_type(16))) float f32x16;
typedef __attribute__((ext_vector_type(4))) unsigned int u32x4;

#define MFMA16(a, b, c) __builtin_amdgcn_mfma_f32_16x16x32_bf16((a), (b), (c), 0, 0, 0)
// reversed operand order: D reg-dim = B-rows (2nd source arg), D lane-dim = A-rows
#define MFMA16R(a, b, c) __builtin_amdgcn_mfma_f32_16x16x32_bf16((b), (a), (c), 0, 0, 0)
#define MFMA32(a, b, c) __builtin_amdgcn_mfma_f32_32x32x16_bf16((a), (b), (c), 0, 0, 0)

// async global->LDS, 16B per lane; LDS dest = wave-uniform base + lane*16
#define GLL16(g, l)                                                        \
  __builtin_amdgcn_global_load_lds(                                        \
      (const __attribute__((address_space(1))) unsigned int*)(g),          \
      (__attribute__((address_space(3))) unsigned int*)(l), 16, 0, 0)

// Fragment-tiled layouts (per (b,h) plane of S_LEN x 64):
__device__ __forceinline__ size_t qk_off(int s, int d) {
  return ((((size_t)(s >> 5) * 4 + (d >> 4)) * 2 + ((d >> 3) & 1)) * 32 + (s & 31)) * 8 + (d & 7);
}
__device__ __forceinline__ size_t v_off(int s, int d) {
  return ((size_t)(s >> 4) * 64 + d) * 16 + (s & 15);
}

// pack two f32 -> one dword of 2 bf16 (lo = first)
__device__ __forceinline__ unsigned pk2(float a, float b) {
  union { __bf16 h[2]; unsigned u; } cv;
  cv.h[0] = (__bf16)a;
  cv.h[1] = (__bf16)b;
  return cv.u;
}

// ---------------- fused prep: x convert + 4 weight converts + rope table ----------
// blocks [0,4096): x f32->bf16 (1048576 float4)
// blocks [4096,8192): weights, 4 planes of 262144 float4
// blocks [8192,8704): rope table tab[i][m] (transposed), 131072 entries
__global__ __launch_bounds__(256) void k_prep(
    const float* __restrict__ x,
    const float* __restrict__ w0, const float* __restrict__ w1,
    const float* __restrict__ w2, const float* __restrict__ w3,
    const int* __restrict__ tpos,
    __bf16* __restrict__ Xb, __bf16* __restrict__ Wdst,
    float2* __restrict__ rtab) {
  const int b = blockIdx.x;
  if (b < 4096) {
    const int i = b * 256 + threadIdx.x;
    const float4 v = reinterpret_cast<const float4*>(x)[i];
    bf16x4 o = { (__bf16)v.x, (__bf16)v.y, (__bf16)v.z, (__bf16)v.w };
    reinterpret_cast<bf16x4*>(Xb)[i] = o;
  } else if (b < 8192) {
    const int bb = b - 4096;
    const int z = bb >> 10;                       // plane 0..3
    const int i = (bb & 1023) * 256 + threadIdx.x;
    const float* src = (z == 0) ? w0 : (z == 1) ? w1 : (z == 2) ? w2 : w3;
    const float4 v = reinterpret_cast<const float4*>(src)[i];
    bf16x4 o = { (__bf16)v.x, (__bf16)v.y, (__bf16)v.z, (__bf16)v.w };
    reinterpret_cast<bf16x4*>(Wdst + (size_t)z * 1048576)[i] = o;
  } else {
    const int idx = (b - 8192) * 256 + threadIdx.x;   // [0, 32*4096)
    const int i = idx >> 12, m = idx & 4095;
    const float invf = exp2f(-(float)i * (13.287712379549449f / 32.0f));
    const float ang = (float)tpos[m] * invf;
    rtab[idx] = make_float2(cosf(ang), sinf(ang));
  }
}

// ================= 128x128 GEMM core, 2-phase load schedule =================
// Per K-step: (1) ds_read ALL frags for both kk sub-steps; (2) barrier (LDS reads
// done block-wide); (3) issue next tile's global_load_lds into the SAME buffer —
// loads fly during (4) the 32 MFMAs; (5) barrier (vmcnt drain finds loads landed).
#define GEMM128_CORE(Abase, Bbase, MFMA_OP)                                    \
  __shared__ __align__(16) __bf16 As[128 * 64];                                \
  __shared__ __align__(16) __bf16 Bs[128 * 64];                                \
  const int t = threadIdx.x;                                                   \
  const int lane = t & 63;                                                     \
  const int w = t >> 6;                                                        \
  const int wm = (w >> 1) * 64;                                                \
  const int wn = (w & 1) * 64;                                                 \
  const int l15 = lane & 15, lhi = lane >> 4;                                  \
  const int lr = lane >> 3;               /* staging row-in-group 0..7 */      \
  const int ls = (lane & 7) ^ lr;         /* swizzled source slot */           \
  const int srow = w * 32 + lr;           /* staging row (+c*8) */             \
  const __bf16* gA = (Abase) + (size_t)(m0 + srow) * DMODEL + ls * 8;          \
  const __bf16* gB = (Bbase) + (size_t)(n0 + srow) * DMODEL + ls * 8;          \
  const f32x4 z4 = {0.f, 0.f, 0.f, 0.f};                                       \
  f32x4 acc[4][4];                                                             \
  _Pragma("unroll") for (int i = 0; i < 4; ++i)                                \
      _Pragma("unroll") for (int j = 0; j < 4; ++j) acc[i][j] = z4;            \
  _Pragma("unroll") for (int c = 0; c < 4; ++c) {                              \
    GLL16(gA + (size_t)c * 8 * DMODEL, &As[w * 2048 + c * 512]);               \
    GLL16(gB + (size_t)c * 8 * DMODEL, &Bs[w * 2048 + c * 512]);               \
  }                                                                            \
  __syncthreads();                                                             \
  for (int k0 = 0; k0 < DMODEL; k0 += 64) {                                    \
    bf16x8 af[2][4], bf[2][4];                                                 \
    _Pragma("unroll") for (int kk = 0; kk < 2; ++kk) {                         \
      const int sw = ((kk * 4 + lhi) ^ (l15 & 7)) * 8;                         \
      _Pragma("unroll") for (int i = 0; i < 4; ++i) {                          \
        af[kk][i] = *reinterpret_cast<const bf16x8*>(                          \
            &As[(wm + i * 16 + l15) * 64 + sw]);                               \
        bf[kk][i] = *reinterpret_cast<const bf16x8*>(                          \
            &Bs[(wn + i * 16 + l15) * 64 + sw]);                               \
      }                                                                        \
    }                                                                          \
    __syncthreads();                  /* all LDS reads done block-wide */      \
    if (k0 + 64 < DMODEL) {                                                    \
      _Pragma("unroll") for (int c = 0; c < 4; ++c) {                          \
        GLL16(gA + (k0 + 64) + (size_t)c * 8 * DMODEL,                         \
              &As[w * 2048 + c * 512]);                                        \
        GLL16(gB + (k0 + 64) + (size_t)c * 8 * DMODEL,                         \
              &Bs[w * 2048 + c * 512]);                                        \
      }                                                                        \
    }                                                                          \
    __builtin_amdgcn_s_setprio(1);                                             \
    _Pragma("unroll") for (int kk = 0; kk < 2; ++kk)                           \
      _Pragma("unroll") for (int i = 0; i < 4; ++i)                            \
          _Pragma("unroll") for (int j = 0; j < 4; ++j)                        \
              acc[i][j] = MFMA_OP(af[kk][i], bf[kk][j], acc[i][j]);            \
    __builtin_amdgcn_s_setprio(0);                                             \
    __syncthreads();                  /* drain: loads overlapped by MFMA */    \
  }

// ---------------- fused QKV projection + RoPE (128x128, swapped operands) ----------
__global__ __launch_bounds__(256) void k_qkv(
    const __bf16* __restrict__ Xb,
    const __bf16* __restrict__ Wqb, const __bf16* __restrict__ Wkb,
    const __bf16* __restrict__ Wvb, const float2* __restrict__ rtab,
    __bf16* __restrict__ Qr, __bf16* __restrict__ Kr, __bf16* __restrict__ Vt) {
  const int z = blockIdx.z;
  const __bf16* W = (z == 0) ? Wqb : (z == 1) ? Wkb : Wvb;
  const int m0 = blockIdx.x * 128;
  const int n0 = blockIdx.y * 128;

  GEMM128_CORE(Xb, W, MFMA16R)

  if (z < 2) {
    __bf16* Out = (z == 0) ? Qr : Kr;
    const float oscale = (z == 0) ? 0.125f * LOG2E : 1.0f;
#pragma unroll
    for (int i = 0; i < 4; ++i) {
      const int m = m0 + wm + i * 16 + l15;
      const int bb = m >> 11, ss = m & (S_LEN - 1);
#pragma unroll
      for (int j = 0; j < 4; ++j) {
        const int ebase = n0 + wn + j * 16 + lhi * 4;
        const int h = ebase >> 6;
        __bf16* plane = Out + (size_t)(bb * NHEAD + h) * (S_LEN * HDK);
#pragma unroll
        for (int rp = 0; rp < 2; ++rp) {
          const int dkI = (ebase + rp * 2) & 63;     // even
          const float2 cssn = rtab[(size_t)(dkI >> 1) * 4096 + m];
          const float x1 = acc[i][j][rp * 2];
          const float x2 = acc[i][j][rp * 2 + 1];
          const float oe = (x1 * cssn.x - x2 * cssn.y) * oscale;
          const float oo = (x1 * cssn.y + x2 * cssn.x) * oscale;
          union { __bf16 h2[2]; ushort2 u2; } pk;
          pk.h2[0] = (__bf16)oe;
          pk.h2[1] = (__bf16)oo;
          *reinterpret_cast<ushort2*>(&plane[qk_off(ss, dkI)]) = pk.u2;
        }
      }
    }
  } else {
#pragma unroll
    for (int i = 0; i < 4; ++i) {
      const int m = m0 + wm + i * 16 + l15;
      const int bb = m >> 11, ss = m & (S_LEN - 1);
#pragma unroll
      for (int j = 0; j < 4; ++j) {
        const int ebase = n0 + wn + j * 16 + lhi * 4;
        const int h = ebase >> 6;
        __bf16* plane = Vt + (size_t)(bb * NHEAD + h) * (S_LEN * HDK);
#pragma unroll
        for (int r = 0; r < 4; ++r) {
          const int d = (ebase + r) & 63;
          plane[v_off(ss, d)] = (__bf16)acc[i][j][r];   // 16-lane 32B runs
        }
      }
    }
  }
}

// ---------------- output projection (128x128, f32 out, normal operand order) ------
__global__ __launch_bounds__(256) void k_oproj(
    const __bf16* __restrict__ Ob, const __bf16* __restrict__ Wob,
    float* __restrict__ out) {
  const int m0 = blockIdx.x * 128;
  const int n0 = blockIdx.y * 128;

  GEMM128_CORE(Ob, Wob, MFMA16)

#pragma unroll
  for (int mi = 0; mi < 4; ++mi) {
#pragma unroll
    for (int ni = 0; ni < 4; ++ni) {
      const int e = n0 + wn + ni * 16 + l15;
#pragma unroll
      for (int r = 0; r < 4; ++r) {
        const int m = m0 + wm + mi * 16 + lhi * 4 + r;
        out[(size_t)m * DMODEL + e] = acc[mi][ni][r];
      }
    }
  }
}

// ---------------- causal flash attention (QBLK=32, 32x32 MFMA, KV-split x2) ----------
// R20-verified structure. Change: bh-MAJOR block mapping (bh = blk>>5) so
// consecutive blocks share the same (b,h) K/V panel -> default block->XCD
// round-robin keeps each head's 1MB panel in its XCD's 4MB L2 (T1 mechanism).
// R15 showed dispatch-order balance is not a factor, so per-head qp order is fine.
__global__ __launch_bounds__(256, 2) void k_attn(
    const __bf16* __restrict__ Qr, const __bf16* __restrict__ Kr,
    const __bf16* __restrict__ Vt, __bf16* __restrict__ Ob) {
  const int t = threadIdx.x, lane = t & 63, w = t >> 6;
  const int blk = blockIdx.x;            // 1024 blocks
  const int bh = blk >> 5;               // bh-major: 32 consecutive blocks per head
  const int qp = blk & 31;               // 0..31 qtile-pair within head
  const int slot = w >> 1;               // which qtile in block (0,1)
  const int half = w & 1;                // k-range half
  const int qtile = (31 - qp) * 2 + slot;  // 0..63, heavy-first within head
  const int q0 = qtile * 32;
  const int l31 = lane & 31, hi = lane >> 5;

  const __bf16* Q = Qr + (size_t)bh * (S_LEN * HDK);
  const __bf16* K = Kr + (size_t)bh * (S_LEN * HDK);
  const __bf16* V = Vt + (size_t)bh * (S_LEN * HDK);

  __shared__ float llb[2][64];               // half1 l
  __shared__ float olb[2][64][33];           // half1 accO, padded

  // Q fragments: row q=l31, d = dc*16 + hi*8 + j  (tiled: dense, lane-stride 16B)
  bf16x8 qf[4];
#pragma unroll
  for (int dc = 0; dc < 4; ++dc)
    qf[dc] = *reinterpret_cast<const bf16x8*>(
        &Q[((((size_t)(q0 >> 5) * 4 + dc) * 2 + hi) * 32 + l31) * 8]);

  f32x16 accO[2] = {};
  float lacc[4] = {0.f, 0.f, 0.f, 0.f};
  const int q = q0 + l31;
  const int kmax = q0 + 32;
  const int kstart = 64 * half;

  // preload K fragments for first k0 of this half
  bf16x8 kf[2][4];
#pragma unroll
  for (int tt = 0; tt < 2; ++tt)
#pragma unroll
    for (int dc = 0; dc < 4; ++dc)
      kf[tt][dc] = *reinterpret_cast<const bf16x8*>(
          &K[((((size_t)((kstart >> 5) + tt) * 4 + dc) * 2 + hi) * 32 + l31) * 8]);

  for (int k0 = kstart; k0 < kmax; k0 += 128) {
    // ---- prefetch V fragments for THIS iteration ----
    bf16x8 vf[4][2];
#pragma unroll
    for (int ttc = 0; ttc < 4; ++ttc) {
      const int kc = k0 + ttc * 16;
#pragma unroll
      for (int d0h = 0; d0h < 2; ++d0h)
        vf[ttc][d0h] = *reinterpret_cast<const bf16x8*>(
            &V[((size_t)(kc >> 4) * 64 + d0h * 32 + l31) * 16 + hi * 8]);
    }

    // ---- QK^T (swapped): two 32k x 32q tiles ----
    f32x16 sT0 = {}, sT1 = {};
    __builtin_amdgcn_s_setprio(1);
#pragma unroll
    for (int dc = 0; dc < 4; ++dc) {
      sT0 = MFMA32(kf[0][dc], qf[dc], sT0);
      sT1 = MFMA32(kf[1][dc], qf[dc], sT1);
    }
    __builtin_amdgcn_s_setprio(0);

    // ---- reload K fragments for NEXT iteration of this half ----
    if (k0 + 128 < kmax) {
      const int kn = (k0 + 128) >> 5;
#pragma unroll
      for (int tt = 0; tt < 2; ++tt)
#pragma unroll
        for (int dc = 0; dc < 4; ++dc)
          kf[tt][dc] = *reinterpret_cast<const bf16x8*>(
              &K[((((size_t)(kn + tt) * 4 + dc) * 2 + hi) * 32 + l31) * 8]);
    }

    // ---- causal mask (diagonal tiles only) ----
    const bool maskIt = (k0 + 63 > q0);
    if (maskIt) {
#pragma unroll
      for (int r = 0; r < 16; ++r) {
        const int kb = (r & 3) + ((r >> 2) << 3) + hi * 4;
        if (k0 + kb > q) sT0[r] = -3e30f;
        if (k0 + 32 + kb > q) sT1[r] = -3e30f;
      }
    }

    // ---- unbiased exp2 + deferred partial sums + pack to bf16 dwords ----
    unsigned pd[16];
#pragma unroll
    for (int j = 0; j < 8; ++j) {
      const float p0 = exp2f(sT0[2 * j]);
      const float p1 = exp2f(sT0[2 * j + 1]);
      const float p2 = exp2f(sT1[2 * j]);
      const float p3 = exp2f(sT1[2 * j + 1]);
      lacc[j & 3] += (p0 + p1) + (p2 + p3);
      pd[j] = pk2(p0, p1);
      pd[8 + j] = pk2(p2, p3);
    }

    // ---- PV: A-frags via permlane32_swap (R14-verified) ----
#pragma unroll
    for (int tt = 0; tt < 2; ++tt) {
#pragma unroll
      for (int c = 0; c < 2; ++c) {
        const int base = tt * 8 + c * 4;
        unsigned u0 = pd[base + 0], u1 = pd[base + 1];
        unsigned u2 = pd[base + 2], u3 = pd[base + 3];
        asm volatile("v_permlane32_swap_b32 %0, %1" : "+v"(u0), "+v"(u2));
        asm volatile("v_permlane32_swap_b32 %0, %1" : "+v"(u1), "+v"(u3));
        union { u32x4 u; bf16x8 v; } cv;
        cv.u = (u32x4){u0, u1, u2, u3};
        const bf16x8 pa = cv.v;
        const int ttc = tt * 2 + c;
        __builtin_amdgcn_s_setprio(1);
        accO[0] = MFMA32(pa, vf[ttc][0], accO[0]);
        accO[1] = MFMA32(pa, vf[ttc][1], accO[1]);
        __builtin_amdgcn_s_setprio(0);
      }
    }
  }

  // ---- fold deferred l: partials + cross-half lane sum (once) ----
  float l_run = (lacc[0] + lacc[1]) + (lacc[2] + lacc[3]);
  l_run += __shfl_xor(l_run, 32);

  // ---- KV-split combine: half1 publishes, half0 merges + stores ----
  if (half == 1) {
    llb[slot][lane] = l_run;
#pragma unroll
    for (int dt = 0; dt < 2; ++dt)
#pragma unroll
      for (int r = 0; r < 16; ++r)
        olb[slot][lane][dt * 16 + r] = accO[dt][r];
  }
  __syncthreads();
  if (half == 0) {
    const float lN = l_run + llb[slot][lane];
    const float inv = 1.0f / lN;         // per q = l31
    float ivr[16];
#pragma unroll
    for (int r = 0; r < 16; ++r) {
      const int qrow = (r & 3) + ((r >> 2) << 3) + hi * 4;
      ivr[r] = __shfl(inv, qrow);
    }
    const int b = bh >> 4, h = bh & 15;
#pragma unroll
    for (int dt = 0; dt < 2; ++dt) {
#pragma unroll
      for (int r = 0; r < 16; ++r) {
        const int qrow = (r & 3) + ((r >> 2) << 3) + hi * 4;
        const int qo = q0 + qrow;
        const float ob = olb[slot][lane][dt * 16 + r];
        const float val = (accO[dt][r] + ob) * ivr[r];
        Ob[((size_t)(b * S_LEN + qo)) * DMODEL + h * HDK + dt * 32 + l31] = (__bf16)val;
      }
    }
  }
}

extern "C" void kernel_launch(void* const* d_in, const int* in_sizes, int n_in,
                              void* d_out, int out_size, void* d_ws, size_t ws_size,
                              hipStream_t stream) {
  const float* x = (const float*)d_in[0];
  const int* tpos = (const int*)d_in[1];
  const float* Wq = (const float*)d_in[2];
  const float* Wk = (const float*)d_in[3];
  const float* Wv = (const float*)d_in[4];
  const float* Wo = (const float*)d_in[5];
  float* out = (float*)d_out;

  __bf16* ws = (__bf16*)d_ws;
  __bf16* Xb = ws;                    // 4096x1024
  __bf16* Wqb = Xb + 4194304;         // 4 x 1024x1024, contiguous
  __bf16* Wkb = Wqb + 1048576;
  __bf16* Wvb = Wkb + 1048576;
  __bf16* Wob = Wvb + 1048576;
  __bf16* Qr = Wob + 1048576;         // [2][16] QK-tiled planes
  __bf16* Kr = Qr + 4194304;
  __bf16* Vt = Kr + 4194304;          // [2][16] V-tiled planes
  __bf16* Ob = Vt + 4194304;          // 4096x1024
  float2* rtab = (float2*)(Ob + 4194304);  // [32][4096] cos/sin (transposed)

  k_prep<<<8704, 256, 0, stream>>>(x, Wq, Wk, Wv, Wo, tpos, Xb, Wqb, rtab);

  dim3 g1(32, 8, 3);
  k_qkv<<<g1, 256, 0, stream>>>(Xb, Wqb, Wkb, Wvb, rtab, Qr, Kr, Vt);

  k_attn<<<1024, 256, 0, stream>>>(Qr, Kr, Vt, Ob);

  dim3 g2(32, 8);
  k_oproj<<<g2, 256, 0, stream>>>(Ob, Wob, out);
}

// Round 22
// 98.299 us; speedup vs baseline: 1.2232x; 1.2232x over previous
//
#include <hip/hip_runtime.h>
#include <hip/hip_bf16.h>
#include <cstdint>
#include <cstddef>

#define S_LEN 2048
#define DMODEL 1024
#define NHEAD 16
#define HDK 64
#define LOG2E 1.44269504088896340736f

typedef __attribute__((ext_vector_type(8))) __bf16 bf16x8;
typedef __attribute__((ext_vector_type(4))) __bf16 bf16x4;
typedef __attribute__((ext_vector_type(4))) float f32x4;
typedef __attribute__((ext_vector_type(16))) float f32x16;
typedef __attribute__((ext_vector_type(4))) unsigned int u32x4;

#define MFMA16(a, b, c) __builtin_amdgcn_mfma_f32_16x16x32_bf16((a), (b), (c), 0, 0, 0)
// reversed operand order: D reg-dim = B-rows (2nd source arg), D lane-dim = A-rows
#define MFMA16R(a, b, c) __builtin_amdgcn_mfma_f32_16x16x32_bf16((b), (a), (c), 0, 0, 0)
#define MFMA32(a, b, c) __builtin_amdgcn_mfma_f32_32x32x16_bf16((a), (b), (c), 0, 0, 0)

// async global->LDS, 16B per lane; LDS dest = wave-uniform base + lane*16
#define GLL16(g, l)                                                        \
  __builtin_amdgcn_global_load_lds(                                        \
      (const __attribute__((address_space(1))) unsigned int*)(g),          \
      (__attribute__((address_space(3))) unsigned int*)(l), 16, 0, 0)

// Fragment-tiled layouts (per (b,h) plane of S_LEN x 64):
__device__ __forceinline__ size_t qk_off(int s, int d) {
  return ((((size_t)(s >> 5) * 4 + (d >> 4)) * 2 + ((d >> 3) & 1)) * 32 + (s & 31)) * 8 + (d & 7);
}
__device__ __forceinline__ size_t v_off(int s, int d) {
  return ((size_t)(s >> 4) * 64 + d) * 16 + (s & 15);
}

// pack two f32 -> one dword of 2 bf16 (lo = first)
__device__ __forceinline__ unsigned pk2(float a, float b) {
  union { __bf16 h[2]; unsigned u; } cv;
  cv.h[0] = (__bf16)a;
  cv.h[1] = (__bf16)b;
  return cv.u;
}

// ---------------- fused prep: x convert + 4 weight converts + rope table ----------
// blocks [0,4096): x f32->bf16 (1048576 float4)
// blocks [4096,8192): weights, 4 planes of 262144 float4
// blocks [8192,8704): rope table tab[i][m] (transposed), 131072 entries
__global__ __launch_bounds__(256) void k_prep(
    const float* __restrict__ x,
    const float* __restrict__ w0, const float* __restrict__ w1,
    const float* __restrict__ w2, const float* __restrict__ w3,
    const int* __restrict__ tpos,
    __bf16* __restrict__ Xb, __bf16* __restrict__ Wdst,
    float2* __restrict__ rtab) {
  const int b = blockIdx.x;
  if (b < 4096) {
    const int i = b * 256 + threadIdx.x;
    const float4 v = reinterpret_cast<const float4*>(x)[i];
    bf16x4 o = { (__bf16)v.x, (__bf16)v.y, (__bf16)v.z, (__bf16)v.w };
    reinterpret_cast<bf16x4*>(Xb)[i] = o;
  } else if (b < 8192) {
    const int bb = b - 4096;
    const int z = bb >> 10;                       // plane 0..3
    const int i = (bb & 1023) * 256 + threadIdx.x;
    const float* src = (z == 0) ? w0 : (z == 1) ? w1 : (z == 2) ? w2 : w3;
    const float4 v = reinterpret_cast<const float4*>(src)[i];
    bf16x4 o = { (__bf16)v.x, (__bf16)v.y, (__bf16)v.z, (__bf16)v.w };
    reinterpret_cast<bf16x4*>(Wdst + (size_t)z * 1048576)[i] = o;
  } else {
    const int idx = (b - 8192) * 256 + threadIdx.x;   // [0, 32*4096)
    const int i = idx >> 12, m = idx & 4095;
    const float invf = exp2f(-(float)i * (13.287712379549449f / 32.0f));
    const float ang = (float)tpos[m] * invf;
    rtab[idx] = make_float2(cosf(ang), sinf(ang));
  }
}

// ================= 128x128 GEMM core, 2-phase load schedule =================
// Per K-step: (1) ds_read ALL frags for both kk sub-steps; (2) barrier (LDS reads
// done block-wide); (3) issue next tile's global_load_lds into the SAME buffer —
// loads fly during (4) the 32 MFMAs; (5) barrier (vmcnt drain finds loads landed).
#define GEMM128_CORE(Abase, Bbase, MFMA_OP)                                    \
  __shared__ __align__(16) __bf16 As[128 * 64];                                \
  __shared__ __align__(16) __bf16 Bs[128 * 64];                                \
  const int t = threadIdx.x;                                                   \
  const int lane = t & 63;                                                     \
  const int w = t >> 6;                                                        \
  const int wm = (w >> 1) * 64;                                                \
  const int wn = (w & 1) * 64;                                                 \
  const int l15 = lane & 15, lhi = lane >> 4;                                  \
  const int lr = lane >> 3;               /* staging row-in-group 0..7 */      \
  const int ls = (lane & 7) ^ lr;         /* swizzled source slot */           \
  const int srow = w * 32 + lr;           /* staging row (+c*8) */             \
  const __bf16* gA = (Abase) + (size_t)(m0 + srow) * DMODEL + ls * 8;          \
  const __bf16* gB = (Bbase) + (size_t)(n0 + srow) * DMODEL + ls * 8;          \
  const f32x4 z4 = {0.f, 0.f, 0.f, 0.f};                                       \
  f32x4 acc[4][4];                                                             \
  _Pragma("unroll") for (int i = 0; i < 4; ++i)                                \
      _Pragma("unroll") for (int j = 0; j < 4; ++j) acc[i][j] = z4;            \
  _Pragma("unroll") for (int c = 0; c < 4; ++c) {                              \
    GLL16(gA + (size_t)c * 8 * DMODEL, &As[w * 2048 + c * 512]);               \
    GLL16(gB + (size_t)c * 8 * DMODEL, &Bs[w * 2048 + c * 512]);               \
  }                                                                            \
  __syncthreads();                                                             \
  for (int k0 = 0; k0 < DMODEL; k0 += 64) {                                    \
    bf16x8 af[2][4], bf[2][4];                                                 \
    _Pragma("unroll") for (int kk = 0; kk < 2; ++kk) {                         \
      const int sw = ((kk * 4 + lhi) ^ (l15 & 7)) * 8;                         \
      _Pragma("unroll") for (int i = 0; i < 4; ++i) {                          \
        af[kk][i] = *reinterpret_cast<const bf16x8*>(                          \
            &As[(wm + i * 16 + l15) * 64 + sw]);                               \
        bf[kk][i] = *reinterpret_cast<const bf16x8*>(                          \
            &Bs[(wn + i * 16 + l15) * 64 + sw]);                               \
      }                                                                        \
    }                                                                          \
    __syncthreads();                  /* all LDS reads done block-wide */      \
    if (k0 + 64 < DMODEL) {                                                    \
      _Pragma("unroll") for (int c = 0; c < 4; ++c) {                          \
        GLL16(gA + (k0 + 64) + (size_t)c * 8 * DMODEL,                         \
              &As[w * 2048 + c * 512]);                                        \
        GLL16(gB + (k0 + 64) + (size_t)c * 8 * DMODEL,                         \
              &Bs[w * 2048 + c * 512]);                                        \
      }                                                                        \
    }                                                                          \
    __builtin_amdgcn_s_setprio(1);                                             \
    _Pragma("unroll") for (int kk = 0; kk < 2; ++kk)                           \
      _Pragma("unroll") for (int i = 0; i < 4; ++i)                            \
          _Pragma("unroll") for (int j = 0; j < 4; ++j)                        \
              acc[i][j] = MFMA_OP(af[kk][i], bf[kk][j], acc[i][j]);            \
    __builtin_amdgcn_s_setprio(0);                                             \
    __syncthreads();                  /* drain: loads overlapped by MFMA */    \
  }

// ---------------- fused QKV projection + RoPE (128x128, swapped operands) ----------
__global__ __launch_bounds__(256) void k_qkv(
    const __bf16* __restrict__ Xb,
    const __bf16* __restrict__ Wqb, const __bf16* __restrict__ Wkb,
    const __bf16* __restrict__ Wvb, const float2* __restrict__ rtab,
    __bf16* __restrict__ Qr, __bf16* __restrict__ Kr, __bf16* __restrict__ Vt) {
  const int z = blockIdx.z;
  const __bf16* W = (z == 0) ? Wqb : (z == 1) ? Wkb : Wvb;
  const int m0 = blockIdx.x * 128;
  const int n0 = blockIdx.y * 128;

  GEMM128_CORE(Xb, W, MFMA16R)

  if (z < 2) {
    __bf16* Out = (z == 0) ? Qr : Kr;
    const float oscale = (z == 0) ? 0.125f * LOG2E : 1.0f;
#pragma unroll
    for (int i = 0; i < 4; ++i) {
      const int m = m0 + wm + i * 16 + l15;
      const int bb = m >> 11, ss = m & (S_LEN - 1);
#pragma unroll
      for (int j = 0; j < 4; ++j) {
        const int ebase = n0 + wn + j * 16 + lhi * 4;
        const int h = ebase >> 6;
        __bf16* plane = Out + (size_t)(bb * NHEAD + h) * (S_LEN * HDK);
#pragma unroll
        for (int rp = 0; rp < 2; ++rp) {
          const int dkI = (ebase + rp * 2) & 63;     // even
          const float2 cssn = rtab[(size_t)(dkI >> 1) * 4096 + m];
          const float x1 = acc[i][j][rp * 2];
          const float x2 = acc[i][j][rp * 2 + 1];
          const float oe = (x1 * cssn.x - x2 * cssn.y) * oscale;
          const float oo = (x1 * cssn.y + x2 * cssn.x) * oscale;
          union { __bf16 h2[2]; ushort2 u2; } pk;
          pk.h2[0] = (__bf16)oe;
          pk.h2[1] = (__bf16)oo;
          *reinterpret_cast<ushort2*>(&plane[qk_off(ss, dkI)]) = pk.u2;
        }
      }
    }
  } else {
#pragma unroll
    for (int i = 0; i < 4; ++i) {
      const int m = m0 + wm + i * 16 + l15;
      const int bb = m >> 11, ss = m & (S_LEN - 1);
#pragma unroll
      for (int j = 0; j < 4; ++j) {
        const int ebase = n0 + wn + j * 16 + lhi * 4;
        const int h = ebase >> 6;
        __bf16* plane = Vt + (size_t)(bb * NHEAD + h) * (S_LEN * HDK);
#pragma unroll
        for (int r = 0; r < 4; ++r) {
          const int d = (ebase + r) & 63;
          plane[v_off(ss, d)] = (__bf16)acc[i][j][r];   // 16-lane 32B runs
        }
      }
    }
  }
}

// ---------------- output projection (128x128, f32 out, normal operand order) ------
__global__ __launch_bounds__(256) void k_oproj(
    const __bf16* __restrict__ Ob, const __bf16* __restrict__ Wob,
    float* __restrict__ out) {
  const int m0 = blockIdx.x * 128;
  const int n0 = blockIdx.y * 128;

  GEMM128_CORE(Ob, Wob, MFMA16)

#pragma unroll
  for (int mi = 0; mi < 4; ++mi) {
#pragma unroll
    for (int ni = 0; ni < 4; ++ni) {
      const int e = n0 + wn + ni * 16 + l15;
#pragma unroll
      for (int r = 0; r < 4; ++r) {
        const int m = m0 + wm + mi * 16 + lhi * 4 + r;
        out[(size_t)m * DMODEL + e] = acc[mi][ni][r];
      }
    }
  }
}

// ---------------- causal flash attention (QBLK=32, 32x32 MFMA, KV-split x2) ----------
// R20-verified structure and block mapping (bh = blk & 31: stride-8 XCD round-robin
// gives each XCD only 4 distinct heads — R21's bh-major inverted this, 5x FETCH).
__global__ __launch_bounds__(256, 2) void k_attn(
    const __bf16* __restrict__ Qr, const __bf16* __restrict__ Kr,
    const __bf16* __restrict__ Vt, __bf16* __restrict__ Ob) {
  const int t = threadIdx.x, lane = t & 63, w = t >> 6;
  const int blk = blockIdx.x;            // 1024 blocks
  const int qp = blk >> 5;               // 0..31 qtile-pair, heavy-first
  const int bh = blk & 31;
  const int slot = w >> 1;               // which qtile in block (0,1)
  const int half = w & 1;                // k-range half
  const int qtile = (31 - qp) * 2 + slot;  // 0..63
  const int q0 = qtile * 32;
  const int l31 = lane & 31, hi = lane >> 5;

  const __bf16* Q = Qr + (size_t)bh * (S_LEN * HDK);
  const __bf16* K = Kr + (size_t)bh * (S_LEN * HDK);
  const __bf16* V = Vt + (size_t)bh * (S_LEN * HDK);

  __shared__ float llb[2][64];               // half1 l
  __shared__ float olb[2][64][33];           // half1 accO, padded

  // Q fragments: row q=l31, d = dc*16 + hi*8 + j  (tiled: dense, lane-stride 16B)
  bf16x8 qf[4];
#pragma unroll
  for (int dc = 0; dc < 4; ++dc)
    qf[dc] = *reinterpret_cast<const bf16x8*>(
        &Q[((((size_t)(q0 >> 5) * 4 + dc) * 2 + hi) * 32 + l31) * 8]);

  f32x16 accO[2] = {};
  float lacc[4] = {0.f, 0.f, 0.f, 0.f};
  const int q = q0 + l31;
  const int kmax = q0 + 32;
  const int kstart = 64 * half;

  // preload K fragments for first k0 of this half
  bf16x8 kf[2][4];
#pragma unroll
  for (int tt = 0; tt < 2; ++tt)
#pragma unroll
    for (int dc = 0; dc < 4; ++dc)
      kf[tt][dc] = *reinterpret_cast<const bf16x8*>(
          &K[((((size_t)((kstart >> 5) + tt) * 4 + dc) * 2 + hi) * 32 + l31) * 8]);

  for (int k0 = kstart; k0 < kmax; k0 += 128) {
    // ---- prefetch V fragments for THIS iteration ----
    bf16x8 vf[4][2];
#pragma unroll
    for (int ttc = 0; ttc < 4; ++ttc) {
      const int kc = k0 + ttc * 16;
#pragma unroll
      for (int d0h = 0; d0h < 2; ++d0h)
        vf[ttc][d0h] = *reinterpret_cast<const bf16x8*>(
            &V[((size_t)(kc >> 4) * 64 + d0h * 32 + l31) * 16 + hi * 8]);
    }

    // ---- QK^T (swapped): two 32k x 32q tiles ----
    f32x16 sT0 = {}, sT1 = {};
    __builtin_amdgcn_s_setprio(1);
#pragma unroll
    for (int dc = 0; dc < 4; ++dc) {
      sT0 = MFMA32(kf[0][dc], qf[dc], sT0);
      sT1 = MFMA32(kf[1][dc], qf[dc], sT1);
    }
    __builtin_amdgcn_s_setprio(0);

    // ---- reload K fragments for NEXT iteration of this half ----
    if (k0 + 128 < kmax) {
      const int kn = (k0 + 128) >> 5;
#pragma unroll
      for (int tt = 0; tt < 2; ++tt)
#pragma unroll
        for (int dc = 0; dc < 4; ++dc)
          kf[tt][dc] = *reinterpret_cast<const bf16x8*>(
              &K[((((size_t)(kn + tt) * 4 + dc) * 2 + hi) * 32 + l31) * 8]);
    }

    // ---- causal mask (diagonal tiles only) ----
    const bool maskIt = (k0 + 63 > q0);
    if (maskIt) {
#pragma unroll
      for (int r = 0; r < 16; ++r) {
        const int kb = (r & 3) + ((r >> 2) << 3) + hi * 4;
        if (k0 + kb > q) sT0[r] = -3e30f;
        if (k0 + 32 + kb > q) sT1[r] = -3e30f;
      }
    }

    // ---- unbiased exp2 + deferred partial sums + pack to bf16 dwords ----
    unsigned pd[16];
#pragma unroll
    for (int j = 0; j < 8; ++j) {
      const float p0 = exp2f(sT0[2 * j]);
      const float p1 = exp2f(sT0[2 * j + 1]);
      const float p2 = exp2f(sT1[2 * j]);
      const float p3 = exp2f(sT1[2 * j + 1]);
      lacc[j & 3] += (p0 + p1) + (p2 + p3);
      pd[j] = pk2(p0, p1);
      pd[8 + j] = pk2(p2, p3);
    }

    // ---- PV: A-frags via permlane32_swap (R14-verified) ----
#pragma unroll
    for (int tt = 0; tt < 2; ++tt) {
#pragma unroll
      for (int c = 0; c < 2; ++c) {
        const int base = tt * 8 + c * 4;
        unsigned u0 = pd[base + 0], u1 = pd[base + 1];
        unsigned u2 = pd[base + 2], u3 = pd[base + 3];
        asm volatile("v_permlane32_swap_b32 %0, %1" : "+v"(u0), "+v"(u2));
        asm volatile("v_permlane32_swap_b32 %0, %1" : "+v"(u1), "+v"(u3));
        union { u32x4 u; bf16x8 v; } cv;
        cv.u = (u32x4){u0, u1, u2, u3};
        const bf16x8 pa = cv.v;
        const int ttc = tt * 2 + c;
        __builtin_amdgcn_s_setprio(1);
        accO[0] = MFMA32(pa, vf[ttc][0], accO[0]);
        accO[1] = MFMA32(pa, vf[ttc][1], accO[1]);
        __builtin_amdgcn_s_setprio(0);
      }
    }
  }

  // ---- fold deferred l: partials + cross-half lane sum (once) ----
  float l_run = (lacc[0] + lacc[1]) + (lacc[2] + lacc[3]);
  l_run += __shfl_xor(l_run, 32);

  // ---- KV-split combine: half1 publishes, half0 merges + stores ----
  if (half == 1) {
    llb[slot][lane] = l_run;
#pragma unroll
    for (int dt = 0; dt < 2; ++dt)
#pragma unroll
      for (int r = 0; r < 16; ++r)
        olb[slot][lane][dt * 16 + r] = accO[dt][r];
  }
  __syncthreads();
  if (half == 0) {
    const float lN = l_run + llb[slot][lane];
    const float inv = 1.0f / lN;         // per q = l31
    float ivr[16];
#pragma unroll
    for (int r = 0; r < 16; ++r) {
      const int qrow = (r & 3) + ((r >> 2) << 3) + hi * 4;
      ivr[r] = __shfl(inv, qrow);
    }
    const int b = bh >> 4, h = bh & 15;
#pragma unroll
    for (int dt = 0; dt < 2; ++dt) {
#pragma unroll
      for (int r = 0; r < 16; ++r) {
        const int qrow = (r & 3) + ((r >> 2) << 3) + hi * 4;
        const int qo = q0 + qrow;
        const float ob = olb[slot][lane][dt * 16 + r];
        const float val = (accO[dt][r] + ob) * ivr[r];
        Ob[((size_t)(b * S_LEN + qo)) * DMODEL + h * HDK + dt * 32 + l31] = (__bf16)val;
      }
    }
  }
}

extern "C" void kernel_launch(void* const* d_in, const int* in_sizes, int n_in,
                              void* d_out, int out_size, void* d_ws, size_t ws_size,
                              hipStream_t stream) {
  const float* x = (const float*)d_in[0];
  const int* tpos = (const int*)d_in[1];
  const float* Wq = (const float*)d_in[2];
  const float* Wk = (const float*)d_in[3];
  const float* Wv = (const float*)d_in[4];
  const float* Wo = (const float*)d_in[5];
  float* out = (float*)d_out;

  __bf16* ws = (__bf16*)d_ws;
  __bf16* Xb = ws;                    // 4096x1024
  __bf16* Wqb = Xb + 4194304;         // 4 x 1024x1024, contiguous
  __bf16* Wkb = Wqb + 1048576;
  __bf16* Wvb = Wkb + 1048576;
  __bf16* Wob = Wvb + 1048576;
  __bf16* Qr = Wob + 1048576;         // [2][16] QK-tiled planes
  __bf16* Kr = Qr + 4194304;
  __bf16* Vt = Kr + 4194304;          // [2][16] V-tiled planes
  __bf16* Ob = Vt + 4194304;          // 4096x1024
  float2* rtab = (float2*)(Ob + 4194304);  // [32][4096] cos/sin (transposed)

  k_prep<<<8704, 256, 0, stream>>>(x, Wq, Wk, Wv, Wo, tpos, Xb, Wqb, rtab);

  dim3 g1(32, 8, 3);
  k_qkv<<<g1, 256, 0, stream>>>(Xb, Wqb, Wkb, Wvb, rtab, Qr, Kr, Vt);

  k_attn<<<1024, 256, 0, stream>>>(Qr, Kr, Vt, Ob);

  dim3 g2(32, 8);
  k_oproj<<<g2, 256, 0, stream>>>(Ob, Wob, out);
}